// Round 3
// baseline (36.604 us; speedup 1.0000x reference)
//
#include <hip/hip_runtime.h>

#define D_MODEL 1024
#define N_MOD   4
#define EBLK    32              // e-chunks in stage 1
#define ECHUNK  (D_MODEL / EBLK)  // 32

typedef float fx4 __attribute__((ext_vector_type(4)));

static __device__ __forceinline__ fx4 ntload(const fx4* p) {
    return __builtin_nontemporal_load(p);
}

// ---------------- Stage 1: partial[m][eb][d] = sum_{e in chunk} Wr[m][e] * Wg[e][d]
// float4-vectorized over d: one block covers all 1024 d (256 threads x float4).
__global__ __launch_bounds__(256) void weff_partial_kernel(
    const fx4* __restrict__ Wg4,      // [1024][256] fx4
    const float* __restrict__ Wr,     // [4][1024]
    fx4* __restrict__ partial4)       // [4][EBLK][256] fx4
{
    const int t  = threadIdx.x;       // d4 index 0..255
    const int eb = blockIdx.x;        // 0..EBLK-1
    fx4 acc[N_MOD];
    #pragma unroll
    for (int m = 0; m < N_MOD; ++m) acc[m] = (fx4)(0.f);

    const int e0 = eb * ECHUNK;
    #pragma unroll 4
    for (int e = e0; e < e0 + ECHUNK; ++e) {
        const fx4 wg = Wg4[e * 256 + t];             // coalesced 4KB/row per block
        #pragma unroll
        for (int m = 0; m < N_MOD; ++m) {
            const float r = Wr[m * D_MODEL + e];     // wave-uniform -> scalar load
            acc[m] += r * wg;                        // contracts to v_fmac via -O3? use fma
        }
    }
    #pragma unroll
    for (int m = 0; m < N_MOD; ++m)
        partial4[(m * EBLK + eb) * 256 + t] = acc[m];
}

// ---------------- Stage 2: Weff[m][d] = sum_eb partial[m][eb][d]
__global__ __launch_bounds__(256) void weff_reduce_kernel(
    const float* __restrict__ partial,  // [4][EBLK][1024]
    float* __restrict__ Weff)           // [4][1024]
{
    const int idx = blockIdx.x * 256 + threadIdx.x;  // 0..4095
    const int m = idx >> 10;
    const int d = idx & (D_MODEL - 1);
    float s = 0.f;
    #pragma unroll
    for (int eb = 0; eb < EBLK; ++eb)
        s += partial[(m * EBLK + eb) * D_MODEL + d];  // coalesced across threads
    Weff[idx] = s;
}

// ---------------- Main: one wave per 2 rows per iteration.
// logits[m] = <h[row], Weff[m]>; probs = softmax; mask = prob>0.5;
// out[m][row][0:4] = mask ? {.5,.5,0,0} : {1,0,0,0}
__global__ __launch_bounds__(256) void router_main_kernel(
    const float* __restrict__ h,     // [B, 1024]
    const float* __restrict__ Weff,  // [4, 1024]
    float* __restrict__ out,         // [4][B][4]
    int B)
{
    const int lane = threadIdx.x & 63;
    const int wave = threadIdx.x >> 6;

    // Each lane caches its Weff slice in registers: w4[m][c] covers d = 4*(c*64+lane)..+3
    fx4 w4[N_MOD][4];
    const fx4* __restrict__ W4 = (const fx4*)Weff;
    #pragma unroll
    for (int m = 0; m < N_MOD; ++m)
        #pragma unroll
        for (int c = 0; c < 4; ++c)
            w4[m][c] = W4[m * 256 + c * 64 + lane];

    float4* __restrict__ out4 = (float4*)out;        // [4][B] float4s
    const int step = gridDim.x * 4 * 2;              // waves * 2 rows

    for (int row = (blockIdx.x * 4 + wave) * 2; row < B; row += step) {
        const fx4* __restrict__ h0 = (const fx4*)(h + (size_t)row * D_MODEL);
        const fx4* __restrict__ h1 = h0 + (D_MODEL / 4);

        // Issue all 8 loads up front so they stay in flight across the reduce.
        fx4 v0[4], v1[4];
        #pragma unroll
        for (int c = 0; c < 4; ++c) v0[c] = ntload(h0 + c * 64 + lane);
        #pragma unroll
        for (int c = 0; c < 4; ++c) v1[c] = ntload(h1 + c * 64 + lane);

        float a0[N_MOD] = {0.f, 0.f, 0.f, 0.f};
        float a1[N_MOD] = {0.f, 0.f, 0.f, 0.f};
        #pragma unroll
        for (int c = 0; c < 4; ++c) {
            #pragma unroll
            for (int m = 0; m < N_MOD; ++m) {
                a0[m] = fmaf(v0[c].x, w4[m][c].x, a0[m]);
                a0[m] = fmaf(v0[c].y, w4[m][c].y, a0[m]);
                a0[m] = fmaf(v0[c].z, w4[m][c].z, a0[m]);
                a0[m] = fmaf(v0[c].w, w4[m][c].w, a0[m]);
                a1[m] = fmaf(v1[c].x, w4[m][c].x, a1[m]);
                a1[m] = fmaf(v1[c].y, w4[m][c].y, a1[m]);
                a1[m] = fmaf(v1[c].z, w4[m][c].z, a1[m]);
                a1[m] = fmaf(v1[c].w, w4[m][c].w, a1[m]);
            }
        }
        // Two independent butterfly chains (ILP).
        #pragma unroll
        for (int off = 32; off; off >>= 1) {
            #pragma unroll
            for (int m = 0; m < N_MOD; ++m) {
                a0[m] += __shfl_xor(a0[m], off, 64);
                a1[m] += __shfl_xor(a1[m], off, 64);
            }
        }
        // prob_m > 0.5  <=>  2*exp(l_m - mx) > sum_j exp(l_j - mx)
        const float mx0 = fmaxf(fmaxf(a0[0], a0[1]), fmaxf(a0[2], a0[3]));
        const float mx1 = fmaxf(fmaxf(a1[0], a1[1]), fmaxf(a1[2], a1[3]));
        float e0[N_MOD], e1[N_MOD], S0 = 0.f, S1 = 0.f;
        #pragma unroll
        for (int m = 0; m < N_MOD; ++m) { e0[m] = expf(a0[m] - mx0); S0 += e0[m]; }
        #pragma unroll
        for (int m = 0; m < N_MOD; ++m) { e1[m] = expf(a1[m] - mx1); S1 += e1[m]; }

        // lanes 0-3 write row, lanes 4-7 write row+1 -> 32B contiguous per module
        if (lane < 8) {
            const int m = lane & 3;
            const int r = lane >> 2;
            const bool hi = r ? (2.f * e1[m] > S1) : (2.f * e0[m] > S0);
            const float4 val = hi ? make_float4(0.5f, 0.5f, 0.f, 0.f)
                                  : make_float4(1.f, 0.f, 0.f, 0.f);
            out4[(size_t)m * B + row + r] = val;
        }
    }
}

extern "C" void kernel_launch(void* const* d_in, const int* in_sizes, int n_in,
                              void* d_out, int out_size, void* d_ws, size_t ws_size,
                              hipStream_t stream) {
    const float* h  = (const float*)d_in[0];   // [B, 1024]
    const float* Wg = (const float*)d_in[1];   // [1024, 1024]
    const float* Wr = (const float*)d_in[2];   // [4, 1024]
    float* out = (float*)d_out;                // [4][B][4]

    const int B = in_sizes[0] / D_MODEL;       // 32768

    float* Weff    = (float*)d_ws;                         // 4096 floats (16 KB)
    float* partial = (float*)d_ws + N_MOD * D_MODEL;       // 4*EBLK*1024 floats (512 KB)

    weff_partial_kernel<<<EBLK, 256, 0, stream>>>(
        (const fx4*)Wg, Wr, (fx4*)partial);

    weff_reduce_kernel<<<(N_MOD * D_MODEL) / 256, 256, 0, stream>>>(partial, Weff);

    router_main_kernel<<<2048, 256, 0, stream>>>(h, Weff, out, B);
}

// Round 4
// 34.686 us; speedup vs baseline: 1.0553x; 1.0553x over previous
//
#include <hip/hip_runtime.h>

#define D_MODEL 1024
#define N_MOD   4
#define EB      32     // e-chunks (cross-block reduction width)
#define DC      4      // d-chunks
#define EPW     8      // e's per esub-wave = (D_MODEL/EB)/4

typedef float fx4 __attribute__((ext_vector_type(4)));

// ---------------- Stage 1: partial[m][eb][d] = sum_{e in chunk eb} Wr[m][e]*Wg[e][d]
// Grid (EB, DC) = 128 blocks. Block: 4 waves = 4 e-sublanes x 64 d4-lanes.
// Each block reads 32 rows x 1KB d-slice = 32KB of Wg, LDS-reduces over esub.
__global__ __launch_bounds__(256) void weff_partial_kernel(
    const fx4* __restrict__ Wg4,   // [1024][256] fx4
    const float* __restrict__ Wr,  // [4][1024]
    fx4* __restrict__ partial4)    // [4][EB][256] fx4
{
    const int t    = threadIdx.x;
    const int esub = t >> 6;        // 0..3 (wave id)
    const int d4   = t & 63;
    const int eb   = blockIdx.x;    // 0..EB-1
    const int dc   = blockIdx.y;    // 0..DC-1
    const int d4g  = dc * 64 + d4;  // global fx4 index 0..255

    const int e0 = eb * (4 * EPW) + esub * EPW;
    fx4 acc[N_MOD];
    #pragma unroll
    for (int m = 0; m < N_MOD; ++m) acc[m] = (fx4)(0.f);

    #pragma unroll
    for (int k = 0; k < EPW; ++k) {
        const int e = e0 + k;
        const fx4 wg = Wg4[e * 256 + d4g];           // 1KB contiguous per wave
        #pragma unroll
        for (int m = 0; m < N_MOD; ++m) {
            const float r = Wr[m * D_MODEL + e];     // wave-uniform scalar load
            acc[m] += r * wg;                        // contracts to fma
        }
    }

    __shared__ fx4 red[4][N_MOD][64];                // 16KB
    #pragma unroll
    for (int m = 0; m < N_MOD; ++m) red[esub][m][d4] = acc[m];
    __syncthreads();

    const int m2 = t >> 6;                           // reuse 256 threads as m x d4
    const fx4 s = red[0][m2][d4] + red[1][m2][d4] + red[2][m2][d4] + red[3][m2][d4];
    partial4[(m2 * EB + eb) * 256 + d4g] = s;
}

// ---------------- Stage 2: Weff[m][d] = sum_eb partial[m][eb][d]
__global__ __launch_bounds__(256) void weff_reduce_kernel(
    const float* __restrict__ partial,  // [4][EB][1024]
    float* __restrict__ Weff)           // [4][1024]
{
    const int idx = blockIdx.x * 256 + threadIdx.x;  // 0..4095
    const int m = idx >> 10;
    const int d = idx & (D_MODEL - 1);
    float s = 0.f;
    #pragma unroll
    for (int eb = 0; eb < EB; ++eb)
        s += partial[(m * EB + eb) * D_MODEL + d];   // coalesced across threads
    Weff[idx] = s;
}

// ---------------- Main: one wave per 2 rows per iteration.
__global__ __launch_bounds__(256) void router_main_kernel(
    const float* __restrict__ h,     // [B, 1024]
    const float* __restrict__ Weff,  // [4, 1024]
    float* __restrict__ out,         // [4][B][4]
    int B)
{
    const int lane = threadIdx.x & 63;
    const int wave = threadIdx.x >> 6;

    fx4 w4[N_MOD][4];
    const fx4* __restrict__ W4 = (const fx4*)Weff;
    #pragma unroll
    for (int m = 0; m < N_MOD; ++m)
        #pragma unroll
        for (int c = 0; c < 4; ++c)
            w4[m][c] = W4[m * 256 + c * 64 + lane];

    float4* __restrict__ out4 = (float4*)out;        // [4][B] float4s
    const int step = gridDim.x * 4 * 2;

    for (int row = (blockIdx.x * 4 + wave) * 2; row < B; row += step) {
        const fx4* __restrict__ h0 = (const fx4*)(h + (size_t)row * D_MODEL);
        const fx4* __restrict__ h1 = h0 + (D_MODEL / 4);

        fx4 v0[4], v1[4];
        #pragma unroll
        for (int c = 0; c < 4; ++c) v0[c] = h0[c * 64 + lane];
        #pragma unroll
        for (int c = 0; c < 4; ++c) v1[c] = h1[c * 64 + lane];

        float a0[N_MOD] = {0.f, 0.f, 0.f, 0.f};
        float a1[N_MOD] = {0.f, 0.f, 0.f, 0.f};
        #pragma unroll
        for (int c = 0; c < 4; ++c) {
            #pragma unroll
            for (int m = 0; m < N_MOD; ++m) {
                a0[m] = fmaf(v0[c].x, w4[m][c].x, a0[m]);
                a0[m] = fmaf(v0[c].y, w4[m][c].y, a0[m]);
                a0[m] = fmaf(v0[c].z, w4[m][c].z, a0[m]);
                a0[m] = fmaf(v0[c].w, w4[m][c].w, a0[m]);
                a1[m] = fmaf(v1[c].x, w4[m][c].x, a1[m]);
                a1[m] = fmaf(v1[c].y, w4[m][c].y, a1[m]);
                a1[m] = fmaf(v1[c].z, w4[m][c].z, a1[m]);
                a1[m] = fmaf(v1[c].w, w4[m][c].w, a1[m]);
            }
        }
        #pragma unroll
        for (int off = 32; off; off >>= 1) {
            #pragma unroll
            for (int m = 0; m < N_MOD; ++m) {
                a0[m] += __shfl_xor(a0[m], off, 64);
                a1[m] += __shfl_xor(a1[m], off, 64);
            }
        }
        const float mx0 = fmaxf(fmaxf(a0[0], a0[1]), fmaxf(a0[2], a0[3]));
        const float mx1 = fmaxf(fmaxf(a1[0], a1[1]), fmaxf(a1[2], a1[3]));
        float e0[N_MOD], e1[N_MOD], S0 = 0.f, S1 = 0.f;
        #pragma unroll
        for (int m = 0; m < N_MOD; ++m) { e0[m] = expf(a0[m] - mx0); S0 += e0[m]; }
        #pragma unroll
        for (int m = 0; m < N_MOD; ++m) { e1[m] = expf(a1[m] - mx1); S1 += e1[m]; }

        if (lane < 8) {
            const int m = lane & 3;
            const int r = lane >> 2;
            const bool hi = r ? (2.f * e1[m] > S1) : (2.f * e0[m] > S0);
            const float4 val = hi ? make_float4(0.5f, 0.5f, 0.f, 0.f)
                                  : make_float4(1.f, 0.f, 0.f, 0.f);
            out4[(size_t)m * B + row + r] = val;
        }
    }
}

extern "C" void kernel_launch(void* const* d_in, const int* in_sizes, int n_in,
                              void* d_out, int out_size, void* d_ws, size_t ws_size,
                              hipStream_t stream) {
    const float* h  = (const float*)d_in[0];   // [B, 1024]
    const float* Wg = (const float*)d_in[1];   // [1024, 1024]
    const float* Wr = (const float*)d_in[2];   // [4, 1024]
    float* out = (float*)d_out;                // [4][B][4]

    const int B = in_sizes[0] / D_MODEL;       // 32768

    float* Weff    = (float*)d_ws;                     // 16 KB
    float* partial = (float*)d_ws + N_MOD * D_MODEL;   // 4*EB*1024 floats = 512 KB

    dim3 g1(EB, DC);
    weff_partial_kernel<<<g1, 256, 0, stream>>>(
        (const fx4*)Wg, Wr, (fx4*)partial);

    weff_reduce_kernel<<<(N_MOD * D_MODEL) / 256, 256, 0, stream>>>(partial, Weff);

    router_main_kernel<<<2048, 256, 0, stream>>>(h, Weff, out, B);
}